// Round 12
// baseline (244.578 us; speedup 1.0000x reference)
//
#include <hip/hip_runtime.h>
#include <stdint.h>

typedef unsigned short u16;
typedef __attribute__((ext_vector_type(8))) short   short8;   // 8 x bf16 bits (4 VGPR)
typedef __attribute__((ext_vector_type(8))) u16     ushort8;
typedef __attribute__((ext_vector_type(4))) float   f32x4;
typedef __attribute__((ext_vector_type(16))) float  f32x16;
typedef __attribute__((ext_vector_type(4))) unsigned int u32x4;

#define SEQ   2048
#define NH    16
#define HD    64
#define DM    1024
#define ROWS  8192   // B*S
#define BHN   64     // B*H

// round-to-nearest-even f32 -> bf16
__device__ __forceinline__ u16 f2bf(float f){
  union { float f; uint32_t u; } v; v.f = f;
  return (u16)((v.u + 0x7fffu + ((v.u >> 16) & 1u)) >> 16);
}

__device__ __forceinline__ unsigned cvtpk(float a, float b){
  unsigned r;
  asm("v_cvt_pk_bf16_f32 %0, %1, %2" : "=v"(r) : "v"(a), "v"(b));
  return r;
}

// v_permlane32_swap_b32: a.hi32lanes <-> b.lo32lanes
__device__ __forceinline__ void pswap(unsigned &a, unsigned &b){
  asm volatile("v_permlane32_swap_b32 %0, %1" : "+v"(a), "+v"(b));
}

// exp2 via builtin (v_exp_f32 is a TRANS op: raw inline asm hides the
// trans->valu hazard from the compiler and corrupts results [R5 lesson]).
__device__ __forceinline__ float fexp2(float x){
  return __builtin_amdgcn_exp2f(x);
}

// pairwise sum tree (fp add not reassociable by compiler)
__device__ __forceinline__ float tsum16(const f32x16& s){
  float a0=s[0]+s[1], a1=s[2]+s[3], a2=s[4]+s[5], a3=s[6]+s[7];
  float a4=s[8]+s[9], a5=s[10]+s[11], a6=s[12]+s[13], a7=s[14]+s[15];
  float b0=a0+a1, b1=a2+a3, b2=a4+a5, b3=a6+a7;
  return (b0+b1)+(b2+b3);
}

#define GAS(p) ((const __attribute__((address_space(1))) void*)(p))
#define LAS(p) ((__attribute__((address_space(3))) void*)(p))

// ----------------------------------------------------- merged prep kernel
// blocks [0,4096): x f32->bf16; [4096,7168): w_qkv transpose; [7168,8192): w_out transpose
__global__ void prep_kernel(const float* __restrict__ x, u16* __restrict__ xb,
                            const float* __restrict__ wqkv, u16* __restrict__ wqkvT,
                            const float* __restrict__ wout, u16* __restrict__ woutT)
{
  __shared__ float tile[32][33];
  const int bid = blockIdx.x, tid = threadIdx.x;
  if (bid < 4096) {
    int i = bid * 256 + tid;                    // exactly 1048576 = ROWS*DM/8
    const float4* p = (const float4*)x + (size_t)i * 2;
    float4 a = p[0], b = p[1];
    ushort8 o;
    o[0]=f2bf(a.x); o[1]=f2bf(a.y); o[2]=f2bf(a.z); o[3]=f2bf(a.w);
    o[4]=f2bf(b.x); o[5]=f2bf(b.y); o[6]=f2bf(b.z); o[7]=f2bf(b.w);
    *(ushort8*)(xb + (size_t)i * 8) = o;
    return;
  }
  const float* in; u16* out; int R, C, bx, by;
  if (bid < 7168) { in = wqkv; out = wqkvT; R = 1024; C = 3072; int b2 = bid - 4096; bx = b2 % 96; by = b2 / 96; }
  else            { in = wout; out = woutT; R = 1024; C = 1024; int b2 = bid - 7168; bx = b2 % 32; by = b2 / 32; }
  int c0 = bx * 32, r0 = by * 32;
  int tx = tid & 31, ty = tid >> 5;             // 32x8
  #pragma unroll
  for (int i = 0; i < 4; i++)
    tile[ty + 8*i][tx] = in[(size_t)(r0 + ty + 8*i) * C + c0 + tx];
  __syncthreads();
  #pragma unroll
  for (int i = 0; i < 4; i++)
    out[(size_t)(c0 + ty + 8*i) * R + r0 + tx] = f2bf(tile[tx][ty + 8*i]);
}

// ---------------------------------------------------------------- GEMM (128^2 m97-style, verified)
#define BM 128
#define BN 128
#define BK 64

template<int MODE>
__global__ __launch_bounds__(256, 2) void gemm_kernel(
    const u16* __restrict__ A, const u16* __restrict__ Bt, const float* __restrict__ bias,
    u16* __restrict__ Qo, u16* __restrict__ Ko, u16* __restrict__ Vto,
    float* __restrict__ Cout)
{
  __shared__ __align__(16) u16 As[BM * BK];
  __shared__ __align__(16) u16 Bs[BN * BK];
  const int tid  = threadIdx.x;
  const int lane = tid & 63, wv = tid >> 6;
  const int wr = wv >> 1, wc = wv & 1;
  const int m0 = blockIdx.y * BM, n0 = blockIdx.x * BN;
  const int K = 1024;

  f32x4 acc[4][4] = {};

  for (int k0 = 0; k0 < K; k0 += BK) {
    #pragma unroll
    for (int i = 0; i < 4; i++) {
      int f = (i * 256 + tid) * 16;
      int row = f >> 7, inrow = f & 127;
      int src = inrow ^ ((row & 7) << 4);
      const u16* ga = A  + (size_t)(m0 + row) * K + k0 + (src >> 1);
      __builtin_amdgcn_global_load_lds(GAS(ga), LAS((char*)As + (i*256 + (wv<<6))*16), 16, 0, 0);
      const u16* gb = Bt + (size_t)(n0 + row) * K + k0 + (src >> 1);
      __builtin_amdgcn_global_load_lds(GAS(gb), LAS((char*)Bs + (i*256 + (wv<<6))*16), 16, 0, 0);
    }
    __syncthreads();
    #pragma unroll
    for (int kk = 0; kk < 2; kk++) {
      short8 af[4], bfr[4];
      #pragma unroll
      for (int i = 0; i < 4; i++) {
        int row = wr*64 + i*16 + (lane & 15);
        int kb  = (kk*64 + 16*(lane >> 4)) ^ ((row & 7) << 4);
        af[i] = *(const short8*)((const char*)As + row*128 + kb);
      }
      #pragma unroll
      for (int j = 0; j < 4; j++) {
        int row = wc*64 + j*16 + (lane & 15);
        int kb  = (kk*64 + 16*(lane >> 4)) ^ ((row & 7) << 4);
        bfr[j] = *(const short8*)((const char*)Bs + row*128 + kb);
      }
      #pragma unroll
      for (int i = 0; i < 4; i++)
        #pragma unroll
        for (int j = 0; j < 4; j++)
          acc[i][j] = __builtin_amdgcn_mfma_f32_16x16x32_bf16(af[i], bfr[j], acc[i][j], 0, 0, 0);
    }
    __syncthreads();
  }

  if (MODE == 0) {
    const int part = n0 >> 10;
    #pragma unroll
    for (int i = 0; i < 4; i++) {
      int row = m0 + wr*64 + i*16 + ((lane >> 4) << 2);
      int b = row >> 11, s = row & 2047;
      #pragma unroll
      for (int j = 0; j < 4; j++) {
        int col = n0 + wc*64 + j*16 + (lane & 15);
        int cn = col & 1023, h = cn >> 6, d = cn & 63;
        int bh = b * NH + h;
        #pragma unroll
        for (int r = 0; r < 4; r++) {
          float v = acc[i][j][r] + bias[col];
          int ss = s + r;
          // Q pre-scale folds 1/sqrt(64) * log2(e) so attention works in exp2 domain
          if (part == 0)      Qo [((size_t)bh*SEQ + ss)*HD + d] = f2bf(v * 0.18033688011f);
          else if (part == 1) Ko [((size_t)bh*SEQ + ss)*HD + d] = f2bf(v);
          else                Vto[((size_t)bh*HD  + d)*SEQ + ss] = f2bf(v);
        }
      }
    }
  } else {
    #pragma unroll
    for (int i = 0; i < 4; i++) {
      int row = m0 + wr*64 + i*16 + ((lane >> 4) << 2);
      #pragma unroll
      for (int j = 0; j < 4; j++) {
        int col = n0 + wc*64 + j*16 + (lane & 15);
        float bv = bias[col];
        #pragma unroll
        for (int r = 0; r < 4; r++)
          Cout[(size_t)(row + r) * DM + col] = acc[i][j][r] + bv;
      }
    }
  }
}

// ---------------------------------------------------------------- flash attention (R12)
// R6 structure (fixed-M softmax, 64 q/wave, in-register P, 4 waves x 64 q, 512 blocks)
// with KVBLK=128: each dbuf slot holds TWO 64-key tile-pairs -> barrier count halved
// (33 -> 17 WAITBARs), 2x compute per drain, 8 staging issues in flight per barrier.
// LDS 64KB x 2 blocks/CU = 128KB.
#define STAGE(LOFF, T) do { \
    _Pragma("unroll") \
    for (int _i = 0; _i < 2; _i++) { \
      int _row = _i * 32 + (tid >> 3); \
      int _src = (((tid & 7) << 4) ^ ((_row & 7) << 4)) >> 1; \
      const u16* _gk = Kg + (((size_t)bh * SEQ + (T) * 64 + _row) << 6) + _src; \
      __builtin_amdgcn_global_load_lds(GAS(_gk), LAS(lds + (LOFF) + _i * 4096 + (wv << 10)), 16, 0, 0); \
      const u16* _gv = Vt + ((size_t)(bh * 64 + _row)) * SEQ + (T) * 64 + _src; \
      __builtin_amdgcn_global_load_lds(GAS(_gv), LAS(lds + (LOFF) + 8192 + _i * 4096 + (wv << 10)), 16, 0, 0); \
    } \
  } while (0)

#define STAGE2(LOFF, T) do { STAGE(LOFF, T); STAGE((LOFF) + 16384, (T) + 1); } while (0)

#define WAITBAR() do { \
    asm volatile("s_waitcnt vmcnt(0) lgkmcnt(0)\n\ts_barrier" ::: "memory"); \
  } while (0)

#define PACK_PA(S, PA0, PA1) do { \
    unsigned a0 = cvtpk((S)[0],  (S)[1]),  b0 = cvtpk((S)[4],  (S)[5]); \
    unsigned a1 = cvtpk((S)[2],  (S)[3]),  b1 = cvtpk((S)[6],  (S)[7]); \
    unsigned a2 = cvtpk((S)[8],  (S)[9]),  b2 = cvtpk((S)[12], (S)[13]); \
    unsigned a3 = cvtpk((S)[10], (S)[11]), b3 = cvtpk((S)[14], (S)[15]); \
    pswap(a0, b0); pswap(a1, b1); pswap(a2, b2); pswap(a3, b3); \
    (PA0).u = (u32x4){a0, a1, b0, b1}; \
    (PA1).u = (u32x4){a2, a3, b2, b3}; \
  } while (0)

#define TILE64(BOFF) do { \
    _Pragma("unroll") \
    for (int H = 0; H < 2; H++) { \
      short8 kf[4]; \
      _Pragma("unroll") \
      for (int kd = 0; kd < 4; kd++) \
        kf[kd] = *(const short8*)(lds + (BOFF) + (32*H + l31) * 128 + ((32*kd + 16*hi) ^ swz)); \
      f32x16 sA, sB; \
      _Pragma("unroll") for (int i = 0; i < 16; i++) { sA[i] = -16.f; sB[i] = -16.f; } \
      __builtin_amdgcn_s_setprio(1); \
      _Pragma("unroll") \
      for (int kd = 0; kd < 4; kd++) { \
        sA = __builtin_amdgcn_mfma_f32_32x32x16_bf16(kf[kd], qfA[kd], sA, 0, 0, 0); \
        sB = __builtin_amdgcn_mfma_f32_32x32x16_bf16(kf[kd], qfB[kd], sB, 0, 0, 0); \
      } \
      __builtin_amdgcn_s_setprio(0); \
      _Pragma("unroll") for (int i = 0; i < 16; i++) { sA[i] = fexp2(sA[i]); sB[i] = fexp2(sB[i]); } \
      lpA += tsum16(sA); lpB += tsum16(sB); \
      union { u32x4 u; short8 s8; } paA0, paA1, paB0, paB1; \
      PACK_PA(sA, paA0, paA1); \
      PACK_PA(sB, paB0, paB1); \
      __builtin_amdgcn_s_setprio(1); \
      _Pragma("unroll") \
      for (int ki = 0; ki < 2; ki++) { \
        int vo = (64*H + 32*ki + 16*hi) ^ swz; \
        short8 vb0 = *(const short8*)(lds + (BOFF) + 8192 + l31 * 128 + vo); \
        short8 vb1 = *(const short8*)(lds + (BOFF) + 12288 + l31 * 128 + vo); \
        const short8 pA = ki ? paA1.s8 : paA0.s8; \
        const short8 pB = ki ? paB1.s8 : paB0.s8; \
        oA0 = __builtin_amdgcn_mfma_f32_32x32x16_bf16(pA, vb0, oA0, 0, 0, 0); \
        oA1 = __builtin_amdgcn_mfma_f32_32x32x16_bf16(pA, vb1, oA1, 0, 0, 0); \
        oB0 = __builtin_amdgcn_mfma_f32_32x32x16_bf16(pB, vb0, oB0, 0, 0, 0); \
        oB1 = __builtin_amdgcn_mfma_f32_32x32x16_bf16(pB, vb1, oB1, 0, 0, 0); \
      } \
      __builtin_amdgcn_s_setprio(0); \
    } \
  } while (0)

__global__ __launch_bounds__(256, 2) void attn_kernel(
    const u16* __restrict__ Q, const u16* __restrict__ Kg,
    const u16* __restrict__ Vt, u16* __restrict__ O)
{
  // LDS: buf0 [K(t) 8K | V(t) 8K | K(t+1) 8K | V(t+1) 8K] @0, buf1 @32768
  __shared__ __align__(16) char lds[65536];
  const int tid = threadIdx.x, lane = tid & 63, wv = tid >> 6;
  const int l31 = lane & 31, hi = lane >> 5;
  const int swz = (lane & 7) << 4;

  // XCD-bijective swizzle: 512 blocks = 8 XCD x 64; each XCD owns 8 whole heads
  int flat = blockIdx.x;
  int nid = (flat & 7) * 64 + (flat >> 3);
  int bh = nid >> 3;
  int q0 = (nid & 7) * 256;

  // two 32-q blocks per wave: rows q0+wv*64+l31 and +32
  short8 qfA[4], qfB[4];
  {
    int qrow = q0 + wv * 64 + l31;
    const u16* qp = Q + (((size_t)bh * SEQ + qrow) << 6) + hi * 8;
    #pragma unroll
    for (int kd = 0; kd < 4; kd++) {
      qfA[kd] = *(const short8*)(qp + kd * 16);
      qfB[kd] = *(const short8*)(qp + 2048 + kd * 16);   // +32 rows * 64
    }
  }

  f32x16 oA0 = {}, oA1 = {}, oB0 = {}, oB1 = {};
  float lpA = 0.f, lpB = 0.f;

  STAGE2(0, 0);
  WAITBAR();
  for (int t = 0; t < 32; t += 4) {
    STAGE2(32768, t + 2);
    TILE64(0);
    TILE64(16384);
    WAITBAR();
    if (t + 4 < 32) STAGE2(0, t + 4);
    TILE64(32768);
    TILE64(49152);
    WAITBAR();
  }

  // epilogue: PV D layout: col(d)=l31, row(q-in-32)=(r&3)+8*(r>>2)+4*hi
  float lfA = lpA + __shfl_xor(lpA, 32);
  float lfB = lpB + __shfl_xor(lpB, 32);
  int b = bh >> 4, h = bh & 15;
  int qbase = q0 + wv * 64;
  #pragma unroll
  for (int r = 0; r < 16; r++) {
    int qrow = (r & 3) + 8 * (r >> 2) + 4 * hi;
    float invA = 1.0f / __shfl(lfA, qrow);
    float invB = 1.0f / __shfl(lfB, qrow);
    size_t rowA = ((size_t)(b * SEQ + qbase + qrow) << 10) + h * 64 + l31;
    size_t rowB = rowA + (32u << 10);
    O[rowA]      = f2bf(oA0[r] * invA);
    O[rowA + 32] = f2bf(oA1[r] * invA);
    O[rowB]      = f2bf(oB0[r] * invB);
    O[rowB + 32] = f2bf(oB1[r] * invB);
  }
}

// ---------------------------------------------------------------- launch
extern "C" void kernel_launch(void* const* d_in, const int* in_sizes, int n_in,
                              void* d_out, int out_size, void* d_ws, size_t ws_size,
                              hipStream_t stream)
{
  const float* x     = (const float*)d_in[0];
  const float* w_qkv = (const float*)d_in[1];
  const float* b_qkv = (const float*)d_in[2];
  const float* w_out = (const float*)d_in[3];
  const float* b_out = (const float*)d_in[4];
  float* out = (float*)d_out;

  char* w = (char*)d_ws;
  u16* xb    = (u16*)(w);                  // 16,777,216 B
  u16* wqkvT = (u16*)(w + 16777216);       //  6,291,456 B
  u16* woutT = (u16*)(w + 23068672);       //  2,097,152 B
  u16* Qw    = (u16*)(w + 25165824);       // 16,777,216 B
  u16* Kw    = (u16*)(w + 41943040);       // 16,777,216 B
  u16* Vtw   = (u16*)(w + 58720256);       // 16,777,216 B
  u16* Ow    = (u16*)(w + 75497472);       // 16,777,216 B

  prep_kernel<<<dim3(8192), dim3(256), 0, stream>>>(x, xb, w_qkv, wqkvT, w_out, woutT);
  gemm_kernel<0><<<dim3(24, 64), dim3(256), 0, stream>>>(xb, wqkvT, b_qkv, Qw, Kw, Vtw, nullptr);
  attn_kernel<<<dim3(512), dim3(256), 0, stream>>>(Qw, Kw, Vtw, Ow);
  gemm_kernel<1><<<dim3(8, 64), dim3(256), 0, stream>>>(Ow, woutT, b_out, nullptr, nullptr, nullptr, out);
}

// Round 13
// 187.279 us; speedup vs baseline: 1.3060x; 1.3060x over previous
//
#include <hip/hip_runtime.h>
#include <stdint.h>

typedef unsigned short u16;
typedef __attribute__((ext_vector_type(8))) short   short8;   // 8 x bf16 bits (4 VGPR)
typedef __attribute__((ext_vector_type(8))) u16     ushort8;
typedef __attribute__((ext_vector_type(4))) float   f32x4;
typedef __attribute__((ext_vector_type(16))) float  f32x16;
typedef __attribute__((ext_vector_type(4))) unsigned int u32x4;

#define SEQ   2048
#define NH    16
#define HD    64
#define DM    1024
#define ROWS  8192   // B*S
#define BHN   64     // B*H

// round-to-nearest-even f32 -> bf16
__device__ __forceinline__ u16 f2bf(float f){
  union { float f; uint32_t u; } v; v.f = f;
  return (u16)((v.u + 0x7fffu + ((v.u >> 16) & 1u)) >> 16);
}

__device__ __forceinline__ unsigned cvtpk(float a, float b){
  unsigned r;
  asm("v_cvt_pk_bf16_f32 %0, %1, %2" : "=v"(r) : "v"(a), "v"(b));
  return r;
}

// v_permlane32_swap_b32: a.hi32lanes <-> b.lo32lanes
__device__ __forceinline__ void pswap(unsigned &a, unsigned &b){
  asm volatile("v_permlane32_swap_b32 %0, %1" : "+v"(a), "+v"(b));
}

// exp2 via builtin (v_exp_f32 is a TRANS op: raw inline asm hides the
// trans->valu hazard from the compiler and corrupts results [R5 lesson]).
__device__ __forceinline__ float fexp2(float x){
  return __builtin_amdgcn_exp2f(x);
}

// pairwise sum tree (fp add not reassociable by compiler)
__device__ __forceinline__ float tsum16(const f32x16& s){
  float a0=s[0]+s[1], a1=s[2]+s[3], a2=s[4]+s[5], a3=s[6]+s[7];
  float a4=s[8]+s[9], a5=s[10]+s[11], a6=s[12]+s[13], a7=s[14]+s[15];
  float b0=a0+a1, b1=a2+a3, b2=a4+a5, b3=a6+a7;
  return (b0+b1)+(b2+b3);
}

#define GAS(p) ((const __attribute__((address_space(1))) void*)(p))
#define LAS(p) ((__attribute__((address_space(3))) void*)(p))

// ----------------------------------------------------- merged prep kernel (R12, verified)
// blocks [0,4096): x f32->bf16; [4096,7168): w_qkv transpose; [7168,8192): w_out transpose
__global__ void prep_kernel(const float* __restrict__ x, u16* __restrict__ xb,
                            const float* __restrict__ wqkv, u16* __restrict__ wqkvT,
                            const float* __restrict__ wout, u16* __restrict__ woutT)
{
  __shared__ float tile[32][33];
  const int bid = blockIdx.x, tid = threadIdx.x;
  if (bid < 4096) {
    int i = bid * 256 + tid;                    // exactly 1048576 = ROWS*DM/8
    const float4* p = (const float4*)x + (size_t)i * 2;
    float4 a = p[0], b = p[1];
    ushort8 o;
    o[0]=f2bf(a.x); o[1]=f2bf(a.y); o[2]=f2bf(a.z); o[3]=f2bf(a.w);
    o[4]=f2bf(b.x); o[5]=f2bf(b.y); o[6]=f2bf(b.z); o[7]=f2bf(b.w);
    *(ushort8*)(xb + (size_t)i * 8) = o;
    return;
  }
  const float* in; u16* out; int R, C, bx, by;
  if (bid < 7168) { in = wqkv; out = wqkvT; R = 1024; C = 3072; int b2 = bid - 4096; bx = b2 % 96; by = b2 / 96; }
  else            { in = wout; out = woutT; R = 1024; C = 1024; int b2 = bid - 7168; bx = b2 % 32; by = b2 / 32; }
  int c0 = bx * 32, r0 = by * 32;
  int tx = tid & 31, ty = tid >> 5;             // 32x8
  #pragma unroll
  for (int i = 0; i < 4; i++)
    tile[ty + 8*i][tx] = in[(size_t)(r0 + ty + 8*i) * C + c0 + tx];
  __syncthreads();
  #pragma unroll
  for (int i = 0; i < 4; i++)
    out[(size_t)(c0 + ty + 8*i) * R + r0 + tx] = f2bf(tile[tx][ty + 8*i]);
}

// ---------------------------------------------------------------- GEMM (128^2 m97-style, verified)
#define BM 128
#define BN 128
#define BK 64

template<int MODE>
__global__ __launch_bounds__(256, 2) void gemm_kernel(
    const u16* __restrict__ A, const u16* __restrict__ Bt, const float* __restrict__ bias,
    u16* __restrict__ Qo, u16* __restrict__ Ko, u16* __restrict__ Vto,
    float* __restrict__ Cout)
{
  __shared__ __align__(16) u16 As[BM * BK];
  __shared__ __align__(16) u16 Bs[BN * BK];
  const int tid  = threadIdx.x;
  const int lane = tid & 63, wv = tid >> 6;
  const int wr = wv >> 1, wc = wv & 1;
  const int m0 = blockIdx.y * BM, n0 = blockIdx.x * BN;
  const int K = 1024;

  f32x4 acc[4][4] = {};

  for (int k0 = 0; k0 < K; k0 += BK) {
    #pragma unroll
    for (int i = 0; i < 4; i++) {
      int f = (i * 256 + tid) * 16;
      int row = f >> 7, inrow = f & 127;
      int src = inrow ^ ((row & 7) << 4);
      const u16* ga = A  + (size_t)(m0 + row) * K + k0 + (src >> 1);
      __builtin_amdgcn_global_load_lds(GAS(ga), LAS((char*)As + (i*256 + (wv<<6))*16), 16, 0, 0);
      const u16* gb = Bt + (size_t)(n0 + row) * K + k0 + (src >> 1);
      __builtin_amdgcn_global_load_lds(GAS(gb), LAS((char*)Bs + (i*256 + (wv<<6))*16), 16, 0, 0);
    }
    __syncthreads();
    #pragma unroll
    for (int kk = 0; kk < 2; kk++) {
      short8 af[4], bfr[4];
      #pragma unroll
      for (int i = 0; i < 4; i++) {
        int row = wr*64 + i*16 + (lane & 15);
        int kb  = (kk*64 + 16*(lane >> 4)) ^ ((row & 7) << 4);
        af[i] = *(const short8*)((const char*)As + row*128 + kb);
      }
      #pragma unroll
      for (int j = 0; j < 4; j++) {
        int row = wc*64 + j*16 + (lane & 15);
        int kb  = (kk*64 + 16*(lane >> 4)) ^ ((row & 7) << 4);
        bfr[j] = *(const short8*)((const char*)Bs + row*128 + kb);
      }
      #pragma unroll
      for (int i = 0; i < 4; i++)
        #pragma unroll
        for (int j = 0; j < 4; j++)
          acc[i][j] = __builtin_amdgcn_mfma_f32_16x16x32_bf16(af[i], bfr[j], acc[i][j], 0, 0, 0);
    }
    __syncthreads();
  }

  if (MODE == 0) {
    const int part = n0 >> 10;
    #pragma unroll
    for (int i = 0; i < 4; i++) {
      int row = m0 + wr*64 + i*16 + ((lane >> 4) << 2);
      int b = row >> 11, s = row & 2047;
      #pragma unroll
      for (int j = 0; j < 4; j++) {
        int col = n0 + wc*64 + j*16 + (lane & 15);
        int cn = col & 1023, h = cn >> 6, d = cn & 63;
        int bh = b * NH + h;
        #pragma unroll
        for (int r = 0; r < 4; r++) {
          float v = acc[i][j][r] + bias[col];
          int ss = s + r;
          // Q pre-scale folds 1/sqrt(64) * log2(e) so attention works in exp2 domain
          if (part == 0)      Qo [((size_t)bh*SEQ + ss)*HD + d] = f2bf(v * 0.18033688011f);
          else if (part == 1) Ko [((size_t)bh*SEQ + ss)*HD + d] = f2bf(v);
          else                Vto[((size_t)bh*HD  + d)*SEQ + ss] = f2bf(v);
        }
      }
    }
  } else {
    #pragma unroll
    for (int i = 0; i < 4; i++) {
      int row = m0 + wr*64 + i*16 + ((lane >> 4) << 2);
      #pragma unroll
      for (int j = 0; j < 4; j++) {
        int col = n0 + wc*64 + j*16 + (lane & 15);
        float bv = bias[col];
        #pragma unroll
        for (int r = 0; r < 4; r++)
          Cout[(size_t)(row + r) * DM + col] = acc[i][j][r] + bv;
      }
    }
  }
}

// ---------------------------------------------------------------- flash attention (R6 exact, verified 81us)
// Fixed-M softmax (M=16 in exp2 domain), 64 q-rows per wave, in-register P via
// cvt_pk+permlane32_swap, dbuf K/V. 4 waves x 64 q = 256 q/block, 512 blocks = 2/CU.
// VGPR=120 <= 128 cap (launch_bounds(256,2)) -- deeper pipelines spill (R12 lesson).
#define STAGE(LOFF, T) do { \
    _Pragma("unroll") \
    for (int _i = 0; _i < 2; _i++) { \
      int _row = _i * 32 + (tid >> 3); \
      int _src = (((tid & 7) << 4) ^ ((_row & 7) << 4)) >> 1; \
      const u16* _gk = Kg + (((size_t)bh * SEQ + (T) * 64 + _row) << 6) + _src; \
      __builtin_amdgcn_global_load_lds(GAS(_gk), LAS(lds + (LOFF) + _i * 4096 + (wv << 10)), 16, 0, 0); \
      const u16* _gv = Vt + ((size_t)(bh * 64 + _row)) * SEQ + (T) * 64 + _src; \
      __builtin_amdgcn_global_load_lds(GAS(_gv), LAS(lds + (LOFF) + 8192 + _i * 4096 + (wv << 10)), 16, 0, 0); \
    } \
  } while (0)

#define WAITBAR() do { \
    asm volatile("s_waitcnt vmcnt(0) lgkmcnt(0)\n\ts_barrier" ::: "memory"); \
  } while (0)

#define PACK_PA(S, PA0, PA1) do { \
    unsigned a0 = cvtpk((S)[0],  (S)[1]),  b0 = cvtpk((S)[4],  (S)[5]); \
    unsigned a1 = cvtpk((S)[2],  (S)[3]),  b1 = cvtpk((S)[6],  (S)[7]); \
    unsigned a2 = cvtpk((S)[8],  (S)[9]),  b2 = cvtpk((S)[12], (S)[13]); \
    unsigned a3 = cvtpk((S)[10], (S)[11]), b3 = cvtpk((S)[14], (S)[15]); \
    pswap(a0, b0); pswap(a1, b1); pswap(a2, b2); pswap(a3, b3); \
    (PA0).u = (u32x4){a0, a1, b0, b1}; \
    (PA1).u = (u32x4){a2, a3, b2, b3}; \
  } while (0)

#define TILE64(BOFF) do { \
    _Pragma("unroll") \
    for (int H = 0; H < 2; H++) { \
      short8 kf[4]; \
      _Pragma("unroll") \
      for (int kd = 0; kd < 4; kd++) \
        kf[kd] = *(const short8*)(lds + (BOFF) + (32*H + l31) * 128 + ((32*kd + 16*hi) ^ swz)); \
      f32x16 sA, sB; \
      _Pragma("unroll") for (int i = 0; i < 16; i++) { sA[i] = -16.f; sB[i] = -16.f; } \
      __builtin_amdgcn_s_setprio(1); \
      _Pragma("unroll") \
      for (int kd = 0; kd < 4; kd++) { \
        sA = __builtin_amdgcn_mfma_f32_32x32x16_bf16(kf[kd], qfA[kd], sA, 0, 0, 0); \
        sB = __builtin_amdgcn_mfma_f32_32x32x16_bf16(kf[kd], qfB[kd], sB, 0, 0, 0); \
      } \
      __builtin_amdgcn_s_setprio(0); \
      _Pragma("unroll") for (int i = 0; i < 16; i++) { sA[i] = fexp2(sA[i]); sB[i] = fexp2(sB[i]); } \
      lpA += tsum16(sA); lpB += tsum16(sB); \
      union { u32x4 u; short8 s8; } paA0, paA1, paB0, paB1; \
      PACK_PA(sA, paA0, paA1); \
      PACK_PA(sB, paB0, paB1); \
      __builtin_amdgcn_s_setprio(1); \
      _Pragma("unroll") \
      for (int ki = 0; ki < 2; ki++) { \
        int vo = (64*H + 32*ki + 16*hi) ^ swz; \
        short8 vb0 = *(const short8*)(lds + (BOFF) + 8192  + l31 * 128 + vo); \
        short8 vb1 = *(const short8*)(lds + (BOFF) + 12288 + l31 * 128 + vo); \
        const short8 pA = ki ? paA1.s8 : paA0.s8; \
        const short8 pB = ki ? paB1.s8 : paB0.s8; \
        oA0 = __builtin_amdgcn_mfma_f32_32x32x16_bf16(pA, vb0, oA0, 0, 0, 0); \
        oA1 = __builtin_amdgcn_mfma_f32_32x32x16_bf16(pA, vb1, oA1, 0, 0, 0); \
        oB0 = __builtin_amdgcn_mfma_f32_32x32x16_bf16(pB, vb0, oB0, 0, 0, 0); \
        oB1 = __builtin_amdgcn_mfma_f32_32x32x16_bf16(pB, vb1, oB1, 0, 0, 0); \
      } \
      __builtin_amdgcn_s_setprio(0); \
    } \
  } while (0)

__global__ __launch_bounds__(256, 2) void attn_kernel(
    const u16* __restrict__ Q, const u16* __restrict__ Kg,
    const u16* __restrict__ Vt, u16* __restrict__ O)
{
  // LDS: [0,8K) K buf0, [8K,16K) V buf0, [16K,24K) K buf1, [24K,32K) V buf1
  __shared__ __align__(16) char lds[32768];
  const int tid = threadIdx.x, lane = tid & 63, wv = tid >> 6;
  const int l31 = lane & 31, hi = lane >> 5;
  const int swz = (lane & 7) << 4;

  // XCD-bijective swizzle: 512 blocks = 8 XCD x 64; each XCD owns 8 whole heads
  int flat = blockIdx.x;
  int nid = (flat & 7) * 64 + (flat >> 3);
  int bh = nid >> 3;
  int q0 = (nid & 7) * 256;

  // two 32-q blocks per wave: rows q0+wv*64+l31 and +32
  short8 qfA[4], qfB[4];
  {
    int qrow = q0 + wv * 64 + l31;
    const u16* qp = Q + (((size_t)bh * SEQ + qrow) << 6) + hi * 8;
    #pragma unroll
    for (int kd = 0; kd < 4; kd++) {
      qfA[kd] = *(const short8*)(qp + kd * 16);
      qfB[kd] = *(const short8*)(qp + 2048 + kd * 16);   // +32 rows * 64
    }
  }

  f32x16 oA0 = {}, oA1 = {}, oB0 = {}, oB1 = {};
  float lpA = 0.f, lpB = 0.f;

  STAGE(0, 0);
  WAITBAR();
  for (int t = 0; t < 32; t += 2) {
    STAGE(16384, t + 1);
    TILE64(0);
    WAITBAR();
    if (t + 2 < 32) STAGE(0, t + 2);
    TILE64(16384);
    WAITBAR();
  }

  // epilogue: PV D layout: col(d)=l31, row(q-in-32)=(r&3)+8*(r>>2)+4*hi
  float lfA = lpA + __shfl_xor(lpA, 32);
  float lfB = lpB + __shfl_xor(lpB, 32);
  int b = bh >> 4, h = bh & 15;
  int qbase = q0 + wv * 64;
  #pragma unroll
  for (int r = 0; r < 16; r++) {
    int qrow = (r & 3) + 8 * (r >> 2) + 4 * hi;
    float invA = 1.0f / __shfl(lfA, qrow);
    float invB = 1.0f / __shfl(lfB, qrow);
    size_t rowA = ((size_t)(b * SEQ + qbase + qrow) << 10) + h * 64 + l31;
    size_t rowB = rowA + (32u << 10);
    O[rowA]      = f2bf(oA0[r] * invA);
    O[rowA + 32] = f2bf(oA1[r] * invA);
    O[rowB]      = f2bf(oB0[r] * invB);
    O[rowB + 32] = f2bf(oB1[r] * invB);
  }
}

// ---------------------------------------------------------------- launch
extern "C" void kernel_launch(void* const* d_in, const int* in_sizes, int n_in,
                              void* d_out, int out_size, void* d_ws, size_t ws_size,
                              hipStream_t stream)
{
  const float* x     = (const float*)d_in[0];
  const float* w_qkv = (const float*)d_in[1];
  const float* b_qkv = (const float*)d_in[2];
  const float* w_out = (const float*)d_in[3];
  const float* b_out = (const float*)d_in[4];
  float* out = (float*)d_out;

  char* w = (char*)d_ws;
  u16* xb    = (u16*)(w);                  // 16,777,216 B
  u16* wqkvT = (u16*)(w + 16777216);       //  6,291,456 B
  u16* woutT = (u16*)(w + 23068672);       //  2,097,152 B
  u16* Qw    = (u16*)(w + 25165824);       // 16,777,216 B
  u16* Kw    = (u16*)(w + 41943040);       // 16,777,216 B
  u16* Vtw   = (u16*)(w + 58720256);       // 16,777,216 B
  u16* Ow    = (u16*)(w + 75497472);       // 16,777,216 B

  prep_kernel<<<dim3(8192), dim3(256), 0, stream>>>(x, xb, w_qkv, wqkvT, w_out, woutT);
  gemm_kernel<0><<<dim3(24, 64), dim3(256), 0, stream>>>(xb, wqkvT, b_qkv, Qw, Kw, Vtw, nullptr);
  attn_kernel<<<dim3(512), dim3(256), 0, stream>>>(Qw, Kw, Vtw, Ow);
  gemm_kernel<1><<<dim3(8, 64), dim3(256), 0, stream>>>(Ow, woutT, b_out, nullptr, nullptr, nullptr, out);
}